// Round 4
// baseline (356.464 us; speedup 1.0000x reference)
//
#include <hip/hip_runtime.h>

// B=2, N=2048, E=2048, H=16, D=128.
// Pipeline: cast fp32->bf16; QKV GEMM split into two exact-round launches:
//   gemm_qk (256 blocks, 256x256 tiles, 4 quadrant-phases/K-tile of 16 MFMA,
//   T1 XCD swizzle + T2 XOR swizzle + T4 counted vmcnt + T5 setprio) -> q|k,
//   gemm_v (256 blocks, 256x128 tiles, 2 ks-phases of 16 MFMA) -> V transposed
//   (vt[b][f][n]) via LDS-transpose epilogue.
// Flash attention S^T formulation + defer-max (T13, THR=8),
// out = y@Wout^T on the same 256x128 exact-round structure (fp32 direct store).

typedef __bf16 bf16;
typedef bf16 bf16x2 __attribute__((ext_vector_type(2)));
typedef bf16 bf16x4 __attribute__((ext_vector_type(4)));
typedef bf16 bf16x8 __attribute__((ext_vector_type(8)));
typedef float f32x4 __attribute__((ext_vector_type(4)));
typedef float f32x16 __attribute__((ext_vector_type(16)));

typedef const __attribute__((address_space(1))) void cg_void;
typedef __attribute__((address_space(3))) void lds_void;

#define MFMA16(a, b, c) __builtin_amdgcn_mfma_f32_16x16x32_bf16((a), (b), (c), 0, 0, 0)
#define MFMA32(a, b, c) __builtin_amdgcn_mfma_f32_32x32x16_bf16((a), (b), (c), 0, 0, 0)

__device__ __forceinline__ void async_load16(const bf16* g, bf16* l) {
  __builtin_amdgcn_global_load_lds((cg_void*)g, (lds_void*)l, 16, 0, 0);
}

// ---------------- merged cast fp32 -> bf16 ----------------
__global__ __launch_bounds__(256) void cast_all_kernel(
    const float* __restrict__ x, const float* __restrict__ wq,
    const float* __restrict__ wkv, const float* __restrict__ wout,
    bf16* __restrict__ xb, bf16* __restrict__ wqkvb, bf16* __restrict__ woutb) {
  long i = (long)blockIdx.x * 256 + threadIdx.x;  // 8-elem chunks
  const float* src; bf16* dst; long off;
  if (i < 1048576)      { src = x;    dst = xb;            off = i; }
  else if (i < 2621440) { src = wq;   dst = wqkvb;         off = i - 1048576;
                          if (off >= 524288) { src = wkv; dst = wqkvb + 4194304; off -= 524288; } }
  else                  { src = wout; dst = woutb;         off = i - 2621440; }
  float4 f0 = ((const float4*)src)[2 * off];
  float4 f1 = ((const float4*)src)[2 * off + 1];
  bf16x8 o;
  o[0] = (bf16)f0.x; o[1] = (bf16)f0.y; o[2] = (bf16)f0.z; o[3] = (bf16)f0.w;
  o[4] = (bf16)f1.x; o[5] = (bf16)f1.y; o[6] = (bf16)f1.z; o[7] = (bf16)f1.w;
  ((bf16x8*)dst)[off] = o;
}

// Staging macros (used inside GEMM kernels; rely on locals Ag/Bg/ldsA/ldsB).
// LDS dest is linear (global_load_lds writes base+lane*16); the XOR swizzle
// (16B chunk ^= row&7) is pre-applied on the GLOBAL source address.
#define STAGE_A(bufi, h, tt) do {                              \
    const bf16* g_ = Ag + (h) * 262144 + (tt) * 64;            \
    bf16* d_ = ldsA + (bufi) * 16384 + (h) * 8192;             \
    async_load16(g_, d_);                                      \
    async_load16(g_ + 131072, d_ + 4096);                      \
  } while (0)
#define STAGE_B(bufi, h, tt) do {                              \
    const bf16* g_ = Bg + (h) * 262144 + (tt) * 64;            \
    bf16* d_ = ldsB + (bufi) * 16384 + (h) * 8192;             \
    async_load16(g_, d_);                                      \
    async_load16(g_ + 131072, d_ + 4096);                      \
  } while (0)
#define STAGE_BS(bufi, tt) do {                                \
    const bf16* g_ = Bg + (tt) * 64;                           \
    bf16* d_ = ldsB + (bufi) * 8192;                           \
    async_load16(g_, d_);                                      \
    async_load16(g_ + 131072, d_ + 4096);                      \
  } while (0)

// ---------------- q|k GEMM: 256x256 tile, 4 quadrant-phases/K-tile ----------
__global__ __launch_bounds__(512, 2)
void gemm_qk_8phase(const bf16* __restrict__ A, const bf16* __restrict__ B,
                    bf16* __restrict__ qk) {
  __shared__ __attribute__((aligned(16))) bf16 sm[2][2][256][64];  // 128 KiB
  const int tid = threadIdx.x;
  const int lane = tid & 63;
  const int wid = tid >> 6;
  const int quad = lane >> 4, l15 = lane & 15;
  const int wr = wid >> 2, wc = wid & 3;   // 2M x 4N waves; wave tile 128x64

  const int lb = (blockIdx.x & 7) * 32 + (blockIdx.x >> 3);
  const int bm = lb >> 4, bn = lb & 15;
  const int m0 = bm * 256, n0 = bn * 256;

  const int srow = tid >> 3;
  const int kswz8 = ((tid & 7) ^ (srow & 7)) * 8;
  const bf16* Ag = A + (size_t)(m0 + srow) * 2048 + kswz8;
  const bf16* Bg = B + (size_t)(n0 + srow) * 2048 + kswz8;
  bf16* ldsA = &sm[0][0][0][0] + tid * 8;
  bf16* ldsB = &sm[1][0][0][0] + tid * 8;

  f32x4 acc[8][4];
#pragma unroll
  for (int i = 0; i < 8; ++i)
#pragma unroll
    for (int j = 0; j < 4; ++j) acc[i][j] = {0.f, 0.f, 0.f, 0.f};

  const int r7 = l15 & 7;
  const int c0 = (quad ^ r7) * 8;        // ks=0 swizzled chunk
  const int c1 = ((4 + quad) ^ r7) * 8;  // ks=1
  const int arow = (wr * 128 + l15) * 64;
  const int brow = (wc * 64 + l15) * 64;

  // prologue: tile0 (buf0) + tile1 A halves (buf1)
  STAGE_A(0, 0, 0); STAGE_A(0, 1, 0); STAGE_B(0, 0, 0); STAGE_B(0, 1, 0);
  STAGE_A(1, 0, 1); STAGE_A(1, 1, 1);
  asm volatile("s_waitcnt vmcnt(4)" ::: "memory");  // tile0 landed
  __builtin_amdgcn_s_barrier();

  for (int t = 0; t < 32; ++t) {
    const int cur = t & 1;
    const bf16* as = &sm[0][0][0][0] + cur * 16384;
    const bf16* bs = &sm[1][0][0][0] + cur * 16384;
    bf16x8 a0[4][2], a1[4][2], b0[2][2], b1[2][2];

    // ---- ph0: q(0,0). reads: A-half0 (8) + B-half0 (4) ----
#pragma unroll
    for (int i = 0; i < 4; ++i) {
      a0[i][0] = *(const bf16x8*)(as + arow + i * 1024 + c0);
      a0[i][1] = *(const bf16x8*)(as + arow + i * 1024 + c1);
    }
#pragma unroll
    for (int j = 0; j < 2; ++j) {
      b0[j][0] = *(const bf16x8*)(bs + brow + j * 1024 + c0);
      b0[j][1] = *(const bf16x8*)(bs + brow + j * 1024 + c1);
    }
    if (t < 31) STAGE_B(1 - cur, 0, t + 1);
    asm volatile("s_waitcnt lgkmcnt(8)" ::: "memory");
    __builtin_amdgcn_s_barrier();
    asm volatile("s_waitcnt lgkmcnt(0)" ::: "memory");
    __builtin_amdgcn_s_setprio(1);
#pragma unroll
    for (int ks = 0; ks < 2; ++ks)
#pragma unroll
      for (int i = 0; i < 4; ++i)
#pragma unroll
        for (int j = 0; j < 2; ++j) acc[i][j] = MFMA16(a0[i][ks], b0[j][ks], acc[i][j]);
    __builtin_amdgcn_s_setprio(0);
    __builtin_amdgcn_s_barrier();

    // ---- ph1: q(0,1). reads: B-half1 (4) ----
#pragma unroll
    for (int j = 0; j < 2; ++j) {
      b1[j][0] = *(const bf16x8*)(bs + brow + (2 + j) * 1024 + c0);
      b1[j][1] = *(const bf16x8*)(bs + brow + (2 + j) * 1024 + c1);
    }
    if (t < 31) STAGE_B(1 - cur, 1, t + 1);
    __builtin_amdgcn_s_barrier();
    asm volatile("s_waitcnt lgkmcnt(0)" ::: "memory");
    __builtin_amdgcn_s_setprio(1);
#pragma unroll
    for (int ks = 0; ks < 2; ++ks)
#pragma unroll
      for (int i = 0; i < 4; ++i)
#pragma unroll
        for (int j = 0; j < 2; ++j) acc[i][2 + j] = MFMA16(a0[i][ks], b1[j][ks], acc[i][2 + j]);
    __builtin_amdgcn_s_setprio(0);
    __builtin_amdgcn_s_barrier();

    // ---- ph2: q(1,0). reads: A-half1 (8) ----
#pragma unroll
    for (int i = 0; i < 4; ++i) {
      a1[i][0] = *(const bf16x8*)(as + arow + (4 + i) * 1024 + c0);
      a1[i][1] = *(const bf16x8*)(as + arow + (4 + i) * 1024 + c1);
    }
    __builtin_amdgcn_s_barrier();
    asm volatile("s_waitcnt lgkmcnt(0)" ::: "memory");
    __builtin_amdgcn_s_setprio(1);
#pragma unroll
    for (int ks = 0; ks < 2; ++ks)
#pragma unroll
      for (int i = 0; i < 4; ++i)
#pragma unroll
        for (int j = 0; j < 2; ++j) acc[4 + i][j] = MFMA16(a1[i][ks], b0[j][ks], acc[4 + i][j]);
    __builtin_amdgcn_s_setprio(0);
    __builtin_amdgcn_s_barrier();

    // ---- ph3: q(1,1). no reads; boundary staging after MFMA ----
    __builtin_amdgcn_s_setprio(1);
#pragma unroll
    for (int ks = 0; ks < 2; ++ks)
#pragma unroll
      for (int i = 0; i < 4; ++i)
#pragma unroll
        for (int j = 0; j < 2; ++j) acc[4 + i][2 + j] = MFMA16(a1[i][ks], b1[j][ks], acc[4 + i][2 + j]);
    __builtin_amdgcn_s_setprio(0);
    if (t < 30) {
      STAGE_A(cur, 0, t + 2); STAGE_A(cur, 1, t + 2);
      asm volatile("s_waitcnt vmcnt(4)" ::: "memory");  // t+1 landed
      __builtin_amdgcn_s_barrier();
    } else if (t == 30) {
      asm volatile("s_waitcnt vmcnt(0)" ::: "memory");
      __builtin_amdgcn_s_barrier();
    }
  }

  // ---- q|k epilogue: direct store, stride 4096 ----
#pragma unroll
  for (int i = 0; i < 8; ++i)
#pragma unroll
    for (int r = 0; r < 4; ++r) {
      const size_t base = (size_t)(m0 + wr * 128 + i * 16 + quad * 4 + r) * 4096
                        + n0 + wc * 64 + l15;
#pragma unroll
      for (int j = 0; j < 4; ++j) qk[base + j * 16] = (bf16)acc[i][j][r];
    }
}

// ---------------- V GEMM: 256x128 tile, 2 ks-phases of 16 MFMA -------------
__global__ __launch_bounds__(512, 2)
void gemm_v_8phase(const bf16* __restrict__ A, const bf16* __restrict__ B,
                   bf16* __restrict__ vt) {
  __shared__ __attribute__((aligned(16))) bf16 smA[2][256][64];  // 64 KiB
  __shared__ __attribute__((aligned(16))) bf16 smB[2][128][64];  // 32 KiB
  const int tid = threadIdx.x;
  const int lane = tid & 63;
  const int wid = tid >> 6;
  const int quad = lane >> 4, l15 = lane & 15;
  const int wr = wid >> 1, wc = wid & 1;   // 4M x 2N waves; wave tile 64x64

  const int lb = (blockIdx.x & 7) * 32 + (blockIdx.x >> 3);
  const int bm = lb >> 4, bn = lb & 15;
  const int m0 = bm * 256, n0 = bn * 128;

  const int srow = tid >> 3;
  const int kswz8 = ((tid & 7) ^ (srow & 7)) * 8;
  const bf16* Ag = A + (size_t)(m0 + srow) * 2048 + kswz8;
  const bf16* Bg = B + (size_t)(n0 + srow) * 2048 + kswz8;
  bf16* ldsA = &smA[0][0][0] + tid * 8;
  bf16* ldsB = &smB[0][0][0] + tid * 8;

  f32x4 acc[4][4];
#pragma unroll
  for (int i = 0; i < 4; ++i)
#pragma unroll
    for (int j = 0; j < 4; ++j) acc[i][j] = {0.f, 0.f, 0.f, 0.f};

  const int r7 = l15 & 7;
  const int arow = (wr * 64 + l15) * 64;
  const int brow = (wc * 64 + l15) * 64;

  STAGE_A(0, 0, 0); STAGE_A(0, 1, 0); STAGE_BS(0, 0);
  STAGE_A(1, 0, 1); STAGE_A(1, 1, 1);
  asm volatile("s_waitcnt vmcnt(4)" ::: "memory");
  __builtin_amdgcn_s_barrier();

  for (int t = 0; t < 32; ++t) {
    const int cur = t & 1;
    const bf16* as = &smA[0][0][0] + cur * 16384;
    const bf16* bs = &smB[0][0][0] + cur * 8192;
#pragma unroll
    for (int ks = 0; ks < 2; ++ks) {
      const int cc = ((ks * 4 + quad) ^ r7) * 8;
      bf16x8 af[4], bfr[4];
#pragma unroll
      for (int i = 0; i < 4; ++i)
        af[i] = *(const bf16x8*)(as + arow + i * 1024 + cc);
#pragma unroll
      for (int j = 0; j < 4; ++j)
        bfr[j] = *(const bf16x8*)(bs + brow + j * 1024 + cc);
      if (ks == 0 && t < 31) STAGE_BS(1 - cur, t + 1);
      __builtin_amdgcn_s_barrier();
      asm volatile("s_waitcnt lgkmcnt(0)" ::: "memory");
      __builtin_amdgcn_s_setprio(1);
#pragma unroll
      for (int i = 0; i < 4; ++i)
#pragma unroll
        for (int j = 0; j < 4; ++j) acc[i][j] = MFMA16(af[i], bfr[j], acc[i][j]);
      __builtin_amdgcn_s_setprio(0);
      __builtin_amdgcn_s_barrier();
    }
    if (t < 30) {
      STAGE_A(cur, 0, t + 2); STAGE_A(cur, 1, t + 2);
      asm volatile("s_waitcnt vmcnt(4)" ::: "memory");
      __builtin_amdgcn_s_barrier();
    } else if (t == 30) {
      asm volatile("s_waitcnt vmcnt(0)" ::: "memory");
      __builtin_amdgcn_s_barrier();
    }
  }

  // ---- V epilogue: transpose 256x128 through LDS -> vt[b][f][n] ----
  __syncthreads();
  bf16* T = &smA[0][0][0];  // [128 f][256 n swizzled] = 64 KiB
#pragma unroll
  for (int i = 0; i < 4; ++i)
#pragma unroll
    for (int r = 0; r < 4; ++r) {
      const int nl = wr * 64 + i * 16 + quad * 4 + r;
#pragma unroll
      for (int j = 0; j < 4; ++j) {
        const int fl = wc * 64 + j * 16 + l15;
        T[fl * 256 + ((((nl >> 3) ^ (fl & 31)) << 3) | (nl & 7))] = (bf16)acc[i][j][r];
      }
    }
  __syncthreads();
  const int f0g = n0, nb0 = m0 & 2047, b = m0 >> 11;
#pragma unroll
  for (int c = 0; c < 8; ++c) {
    const int idx = c * 512 + tid;
    const int fl = idx >> 5, nb = idx & 31;
    bf16x8 o = *(const bf16x8*)(T + fl * 256 + ((nb ^ (fl & 31)) << 3));
    *(bf16x8*)(vt + (size_t)(b * 2048 + f0g + fl) * 2048 + nb0 + nb * 8) = o;
  }
}

// ---------------- out-proj: 256x128 tile, exact-round, fp32 direct store ----
// C[4096,2048] = A[4096,2048] * B[2048,2048]^T. Same structure as gemm_v
// (8 waves, 2 ks-phases of 16 MFMA, counted vmcnt, T1/T2/T5); epilogue is a
// plain fp32 store (no transpose). Grid 256 blocks (16x16) = one exact round.
__global__ __launch_bounds__(512, 2)
void gemm_out_v2(const bf16* __restrict__ A, const bf16* __restrict__ B,
                 float* __restrict__ C) {
  __shared__ __attribute__((aligned(16))) bf16 smA[2][256][64];  // 64 KiB
  __shared__ __attribute__((aligned(16))) bf16 smB[2][128][64];  // 32 KiB
  const int tid = threadIdx.x;
  const int lane = tid & 63;
  const int wid = tid >> 6;
  const int quad = lane >> 4, l15 = lane & 15;
  const int wr = wid >> 1, wc = wid & 1;   // 4M x 2N waves; wave tile 64x64

  const int lb = (blockIdx.x & 7) * 32 + (blockIdx.x >> 3);
  const int bm = lb >> 4, bn = lb & 15;
  const int m0 = bm * 256, n0 = bn * 128;

  const int srow = tid >> 3;
  const int kswz8 = ((tid & 7) ^ (srow & 7)) * 8;
  const bf16* Ag = A + (size_t)(m0 + srow) * 2048 + kswz8;
  const bf16* Bg = B + (size_t)(n0 + srow) * 2048 + kswz8;
  bf16* ldsA = &smA[0][0][0] + tid * 8;
  bf16* ldsB = &smB[0][0][0] + tid * 8;

  f32x4 acc[4][4];
#pragma unroll
  for (int i = 0; i < 4; ++i)
#pragma unroll
    for (int j = 0; j < 4; ++j) acc[i][j] = {0.f, 0.f, 0.f, 0.f};

  const int r7 = l15 & 7;
  const int arow = (wr * 64 + l15) * 64;
  const int brow = (wc * 64 + l15) * 64;

  STAGE_A(0, 0, 0); STAGE_A(0, 1, 0); STAGE_BS(0, 0);
  STAGE_A(1, 0, 1); STAGE_A(1, 1, 1);
  asm volatile("s_waitcnt vmcnt(4)" ::: "memory");
  __builtin_amdgcn_s_barrier();

  for (int t = 0; t < 32; ++t) {
    const int cur = t & 1;
    const bf16* as = &smA[0][0][0] + cur * 16384;
    const bf16* bs = &smB[0][0][0] + cur * 8192;
#pragma unroll
    for (int ks = 0; ks < 2; ++ks) {
      const int cc = ((ks * 4 + quad) ^ r7) * 8;
      bf16x8 af[4], bfr[4];
#pragma unroll
      for (int i = 0; i < 4; ++i)
        af[i] = *(const bf16x8*)(as + arow + i * 1024 + cc);
#pragma unroll
      for (int j = 0; j < 4; ++j)
        bfr[j] = *(const bf16x8*)(bs + brow + j * 1024 + cc);
      if (ks == 0 && t < 31) STAGE_BS(1 - cur, t + 1);
      __builtin_amdgcn_s_barrier();
      asm volatile("s_waitcnt lgkmcnt(0)" ::: "memory");
      __builtin_amdgcn_s_setprio(1);
#pragma unroll
      for (int i = 0; i < 4; ++i)
#pragma unroll
        for (int j = 0; j < 4; ++j) acc[i][j] = MFMA16(af[i], bfr[j], acc[i][j]);
      __builtin_amdgcn_s_setprio(0);
      __builtin_amdgcn_s_barrier();
    }
    if (t < 30) {
      STAGE_A(cur, 0, t + 2); STAGE_A(cur, 1, t + 2);
      asm volatile("s_waitcnt vmcnt(4)" ::: "memory");
      __builtin_amdgcn_s_barrier();
    } else if (t == 30) {
      asm volatile("s_waitcnt vmcnt(0)" ::: "memory");
      __builtin_amdgcn_s_barrier();
    }
  }

  // ---- fp32 direct store ----
#pragma unroll
  for (int i = 0; i < 4; ++i) {
#pragma unroll
    for (int r = 0; r < 4; ++r) {
      const size_t base = (size_t)(m0 + wr * 64 + i * 16 + quad * 4 + r) * 2048
                        + n0 + wc * 64 + l15;
#pragma unroll
      for (int j = 0; j < 4; ++j) C[base + j * 16] = (float)acc[i][j][r];
    }
  }
}

// ---------------- flash attention, causal, S^T, double-buffered --------------
// Defer-max (T13): skip the O-rescale + m-update when the tile max grew by
// <= 8 in exp2 domain (P bounded by 2^8; f32 accumulator absorbs the scale).
__global__ __launch_bounds__(256, 2)
void attn_kernel(const bf16* __restrict__ qk, const bf16* __restrict__ vt,
                 bf16* __restrict__ yb) {
  constexpr int NSEQ = 2048, E = 2048, QKS = 4096;
  __shared__ __attribute__((aligned(16))) bf16 Ks[2][64 * 128];   // [tok][d], XOR-swizzled
  __shared__ __attribute__((aligned(16))) bf16 Vs[2][128 * 64];   // [d][tok], XOR-swizzled
  const int tid = threadIdx.x;
  const int wave = tid >> 6, lane = tid & 63;
  const int l31 = lane & 31, half = lane >> 5;
  const int id = blockIdx.x;
  const int slot = (id >> 5) & 15;
  const int bh = (id & 7) | (((id >> 3) & 3) << 3);
  const int b = bh >> 4, h = bh & 15;
  const int qt = (slot < 8) ? slot : 23 - slot;
  const float c1 = 0.08838834764831845f * 1.44269504088896f;  // scale * log2(e)

  const int krow_s = tid >> 4, kch_s = tid & 15;  // K: 16 chunks/row
  const int vrow_s = tid >> 3, vch_s = tid & 7;   // V: 8 chunks/row
  const bf16* kg = qk + (size_t)(b * NSEQ) * QKS + 2048 + h * 128;
  const bf16* vg = vt + (size_t)b * E * NSEQ + (size_t)(h * 128) * NSEQ;

  const int diag = 2 * qt + (wave >> 1);
  const int ktmax = 2 * qt + 1;

  {
    bf16* kdst = Ks[0] + tid * 8;
    bf16* vdst = Vs[0] + tid * 8;
#pragma unroll
    for (int p = 0; p < 4; ++p) {
      int r = p * 16 + krow_s;
      async_load16(kg + (size_t)r * QKS + (kch_s ^ (r & 7)) * 8, kdst + p * 2048);
    }
#pragma unroll
    for (int p = 0; p < 4; ++p) {
      int r = p * 32 + vrow_s;
      async_load16(vg + (size_t)r * NSEQ + (vch_s ^ (r & 7)) * 8, vdst + p * 2048);
    }
  }

  const int qrow = qt * 128 + wave * 32 + l31;
  bf16x8 qf[8];
  {
    const bf16* qp = qk + (size_t)(b * NSEQ + qrow) * QKS + h * 128 + half * 8;
#pragma unroll
    for (int k8 = 0; k8 < 8; ++k8) qf[k8] = *(const bf16x8*)(qp + k8 * 16);
  }

  float m = -3.0e38f, l = 0.f;
  f32x16 accO[4];
#pragma unroll
  for (int md = 0; md < 4; ++md)
#pragma unroll
    for (int r = 0; r < 16; ++r) accO[md][r] = 0.f;

  union PU { unsigned u; bf16x2 h; };
  union FU { bf16x8 v; unsigned u[4]; };

  for (int kt = 0; kt <= ktmax; ++kt) {
    const int cur = kt & 1;
    __syncthreads();

    if (kt < ktmax) {
      const int nxt = kt + 1;
      bf16* kdst = Ks[1 - cur] + tid * 8;
      bf16* vdst = Vs[1 - cur] + tid * 8;
#pragma unroll
      for (int p = 0; p < 4; ++p) {
        int r = p * 16 + krow_s;
        async_load16(kg + (size_t)(nxt * 64 + r) * QKS + (kch_s ^ (r & 7)) * 8, kdst + p * 2048);
      }
#pragma unroll
      for (int p = 0; p < 4; ++p) {
        int r = p * 32 + vrow_s;
        async_load16(vg + (size_t)r * NSEQ + nxt * 64 + (vch_s ^ (r & 7)) * 8, vdst + p * 2048);
      }
    }

    if (kt > diag) continue;

    const bf16* ks = Ks[cur];
    const bf16* vs = Vs[cur];

    f32x16 st[2];
#pragma unroll
    for (int mt = 0; mt < 2; ++mt)
#pragma unroll
      for (int r = 0; r < 16; ++r) st[mt][r] = 0.f;
#pragma unroll
    for (int k8 = 0; k8 < 8; ++k8) {
#pragma unroll
      for (int mt = 0; mt < 2; ++mt) {
        int row = mt * 32 + l31;
        int sl = (k8 * 2 + half) ^ (row & 7);
        bf16x8 kf = *(const bf16x8*)(ks + row * 128 + sl * 8);
        st[mt] = MFMA32(kf, qf[k8], st[mt]);
      }
    }

    if (kt == diag) {
#pragma unroll
      for (int mt = 0; mt < 2; ++mt)
#pragma unroll
        for (int r = 0; r < 16; ++r) {
          int t = kt * 64 + mt * 32 + (r & 3) + 8 * (r >> 2) + 4 * half;
          if (t > qrow) st[mt][r] = -3.0e38f;
        }
    }

    // ---- online softmax with defer-max (T13) ----
    float mx = -3.0e38f;
#pragma unroll
    for (int mt = 0; mt < 2; ++mt)
#pragma unroll
      for (int r = 0; r < 16; ++r) mx = fmaxf(mx, st[mt][r]);
    mx = fmaxf(mx, __shfl_xor(mx, 32));

    const bool noresc = __all((mx - m) * c1 <= 8.0f);
    const float mnew = noresc ? m : fmaxf(m, mx);
    const float mc = mnew * c1;

    float psum = 0.f;
    unsigned pown[2][4][2];
#pragma unroll
    for (int mt = 0; mt < 2; ++mt)
#pragma unroll
      for (int qd = 0; qd < 4; ++qd)
#pragma unroll
        for (int pr = 0; pr < 2; ++pr) {
          float p0 = exp2f(st[mt][qd * 4 + pr * 2] * c1 - mc);
          float p1 = exp2f(st[mt][qd * 4 + pr * 2 + 1] * c1 - mc);
          psum += p0 + p1;
          PU a; a.h[0] = (bf16)p0; a.h[1] = (bf16)p1;
          pown[mt][qd][pr] = a.u;
        }
    psum += __shfl_xor(psum, 32);

    if (!noresc) {
      const float alpha = exp2f((m - mnew) * c1);
      l *= alpha;
      m = mnew;
#pragma unroll
      for (int md = 0; md < 4; ++md)
#pragma unroll
        for (int r = 0; r < 16; ++r) accO[md][r] *= alpha;
    }
    l += psum;

#pragma unroll
    for (int mt = 0; mt < 2; ++mt)
#pragma unroll
      for (int c = 0; c < 2; ++c) {
        const int qa = 2 * c, qb = 2 * c + 1;
        unsigned ra0 = __shfl_xor(pown[mt][qa][0], 32);
        unsigned ra1 = __shfl_xor(pown[mt][qa][1], 32);
        unsigned rb0 = __shfl_xor(pown[mt][qb][0], 32);
        unsigned rb1 = __shfl_xor(pown[mt][qb][1], 32);
        FU f;
        f.u[0] = half ? rb0 : pown[mt][qa][0];
        f.u[1] = half ? rb1 : pown[mt][qa][1];
        f.u[2] = half ? pown[mt][qb][0] : ra0;
        f.u[3] = half ? pown[mt][qb][1] : ra1;
        const int kk = mt * 2 + c;
#pragma unroll
        for (int md = 0; md < 4; ++md) {
          int row = md * 32 + l31;
          bf16x8 vf = *(const bf16x8*)(vs + row * 64 + (((kk * 2 + half) ^ (row & 7)) * 8));
          accO[md] = MFMA32(vf, f.v, accO[md]);
        }
      }
  }

  float invl = 1.0f / l;
  bf16* yp = yb + (size_t)(b * NSEQ + qrow) * E + h * 128;
#pragma unroll
  for (int md = 0; md < 4; ++md)
#pragma unroll
    for (int rq = 0; rq < 4; ++rq) {
      bf16x4 o;
#pragma unroll
      for (int i = 0; i < 4; ++i) o[i] = (bf16)(accO[md][rq * 4 + i] * invl);
      *(bf16x4*)(yp + md * 32 + rq * 8 + half * 4) = o;
    }
}

// ---------------- launch ----------------
extern "C" void kernel_launch(void* const* d_in, const int* in_sizes, int n_in,
                              void* d_out, int out_size, void* d_ws, size_t ws_size,
                              hipStream_t stream) {
  const float* x    = (const float*)d_in[0];
  const float* Wq   = (const float*)d_in[1];
  const float* Wkv  = (const float*)d_in[2];
  const float* Wout = (const float*)d_in[3];
  float* out = (float*)d_out;

  constexpr size_t NX = (size_t)2 * 2048 * 2048;  // 8388608
  constexpr size_t NW = (size_t)2048 * 2048;      // 4194304

  bf16* xb     = (bf16*)d_ws;
  bf16* wqkvb  = xb + NX;          // [6144 x 2048] = Wq rows then Wkv rows
  bf16* woutb  = wqkvb + 3 * NW;
  bf16* qk_b   = woutb + NW;       // [4096 x 4096]: q | k per row
  bf16* y_b    = qk_b + 2 * NX;
  bf16* vt_b   = y_b + NX;         // [b, f, n] = [2][2048][2048]

  cast_all_kernel<<<12288, 256, 0, stream>>>(x, Wq, Wkv, Wout, xb, wqkvb, woutb);

  // q|k = x @ [Wq; Wk]^T -> qk_b (stride 4096); one exact 256-block round
  gemm_qk_8phase<<<256, 512, 0, stream>>>(xb, wqkvb, qk_b);
  // V = x @ Wv^T -> vt_b transposed; one exact 256-block round
  gemm_v_8phase<<<256, 512, 0, stream>>>(xb, wqkvb + (size_t)4096 * 2048, vt_b);
  // attention -> y [4096, 2048] bf16
  attn_kernel<<<512, 256, 0, stream>>>(qk_b, vt_b, y_b);
  // out = y @ Wout^T : fp32, one exact 256-block round
  gemm_out_v2<<<256, 512, 0, stream>>>(y_b, woutb, out);
}

// Round 5
// 346.832 us; speedup vs baseline: 1.0278x; 1.0278x over previous
//
#include <hip/hip_runtime.h>

// B=2, N=2048, E=2048, H=16, D=128.
// Pipeline: cast fp32->bf16; gemm_qk (256 blocks, 256x256, 4 quadrant-phases,
// T1/T2/T4/T5) -> q|k; gemm_thin<0> (256 blocks, 256x128, 2-K-tile deepened
// 4-phase schedule, spread staging, vmcnt(4)/vmcnt(6) counted waits) -> V
// transposed vt[b][f][n]; flash attention S^T + defer-max; gemm_thin<1>
// (same deepened template, fp32 direct store) -> out.

typedef __bf16 bf16;
typedef bf16 bf16x2 __attribute__((ext_vector_type(2)));
typedef bf16 bf16x4 __attribute__((ext_vector_type(4)));
typedef bf16 bf16x8 __attribute__((ext_vector_type(8)));
typedef float f32x4 __attribute__((ext_vector_type(4)));
typedef float f32x16 __attribute__((ext_vector_type(16)));

typedef const __attribute__((address_space(1))) void cg_void;
typedef __attribute__((address_space(3))) void lds_void;

#define MFMA16(a, b, c) __builtin_amdgcn_mfma_f32_16x16x32_bf16((a), (b), (c), 0, 0, 0)
#define MFMA32(a, b, c) __builtin_amdgcn_mfma_f32_32x32x16_bf16((a), (b), (c), 0, 0, 0)

__device__ __forceinline__ void async_load16(const bf16* g, bf16* l) {
  __builtin_amdgcn_global_load_lds((cg_void*)g, (lds_void*)l, 16, 0, 0);
}

// ---------------- merged cast fp32 -> bf16 ----------------
__global__ __launch_bounds__(256) void cast_all_kernel(
    const float* __restrict__ x, const float* __restrict__ wq,
    const float* __restrict__ wkv, const float* __restrict__ wout,
    bf16* __restrict__ xb, bf16* __restrict__ wqkvb, bf16* __restrict__ woutb) {
  long i = (long)blockIdx.x * 256 + threadIdx.x;  // 8-elem chunks
  const float* src; bf16* dst; long off;
  if (i < 1048576)      { src = x;    dst = xb;            off = i; }
  else if (i < 2621440) { src = wq;   dst = wqkvb;         off = i - 1048576;
                          if (off >= 524288) { src = wkv; dst = wqkvb + 4194304; off -= 524288; } }
  else                  { src = wout; dst = woutb;         off = i - 2621440; }
  float4 f0 = ((const float4*)src)[2 * off];
  float4 f1 = ((const float4*)src)[2 * off + 1];
  bf16x8 o;
  o[0] = (bf16)f0.x; o[1] = (bf16)f0.y; o[2] = (bf16)f0.z; o[3] = (bf16)f0.w;
  o[4] = (bf16)f1.x; o[5] = (bf16)f1.y; o[6] = (bf16)f1.z; o[7] = (bf16)f1.w;
  ((bf16x8*)dst)[off] = o;
}

// Staging macros (use locals Ag/Bg/ldsA/ldsB). LDS dest is linear
// (global_load_lds writes base+lane*16); the XOR swizzle (16B chunk ^= row&7)
// is pre-applied on the GLOBAL source address.
#define STAGE_A(bufi, h, tt) do {                              \
    const bf16* g_ = Ag + (h) * 262144 + (tt) * 64;            \
    bf16* d_ = ldsA + (bufi) * 16384 + (h) * 8192;             \
    async_load16(g_, d_);                                      \
    async_load16(g_ + 131072, d_ + 4096);                      \
  } while (0)
#define STAGE_B(bufi, h, tt) do {                              \
    const bf16* g_ = Bg + (h) * 262144 + (tt) * 64;            \
    bf16* d_ = ldsB + (bufi) * 16384 + (h) * 8192;             \
    async_load16(g_, d_);                                      \
    async_load16(g_ + 131072, d_ + 4096);                      \
  } while (0)
#define STAGE_BS(bufi, tt) do {                                \
    const bf16* g_ = Bg + (tt) * 64;                           \
    bf16* d_ = ldsB + (bufi) * 8192;                           \
    async_load16(g_, d_);                                      \
    async_load16(g_ + 131072, d_ + 4096);                      \
  } while (0)

// ---------------- q|k GEMM: 256x256 tile, 4 quadrant-phases/K-tile ----------
// (unchanged from R3/R4 — control)
__global__ __launch_bounds__(512, 2)
void gemm_qk_8phase(const bf16* __restrict__ A, const bf16* __restrict__ B,
                    bf16* __restrict__ qk) {
  __shared__ __attribute__((aligned(16))) bf16 sm[2][2][256][64];  // 128 KiB
  const int tid = threadIdx.x;
  const int lane = tid & 63;
  const int wid = tid >> 6;
  const int quad = lane >> 4, l15 = lane & 15;
  const int wr = wid >> 2, wc = wid & 3;   // 2M x 4N waves; wave tile 128x64

  const int lb = (blockIdx.x & 7) * 32 + (blockIdx.x >> 3);
  const int bm = lb >> 4, bn = lb & 15;
  const int m0 = bm * 256, n0 = bn * 256;

  const int srow = tid >> 3;
  const int kswz8 = ((tid & 7) ^ (srow & 7)) * 8;
  const bf16* Ag = A + (size_t)(m0 + srow) * 2048 + kswz8;
  const bf16* Bg = B + (size_t)(n0 + srow) * 2048 + kswz8;
  bf16* ldsA = &sm[0][0][0][0] + tid * 8;
  bf16* ldsB = &sm[1][0][0][0] + tid * 8;

  f32x4 acc[8][4];
#pragma unroll
  for (int i = 0; i < 8; ++i)
#pragma unroll
    for (int j = 0; j < 4; ++j) acc[i][j] = {0.f, 0.f, 0.f, 0.f};

  const int r7 = l15 & 7;
  const int c0 = (quad ^ r7) * 8;        // ks=0 swizzled chunk
  const int c1 = ((4 + quad) ^ r7) * 8;  // ks=1
  const int arow = (wr * 128 + l15) * 64;
  const int brow = (wc * 64 + l15) * 64;

  STAGE_A(0, 0, 0); STAGE_A(0, 1, 0); STAGE_B(0, 0, 0); STAGE_B(0, 1, 0);
  STAGE_A(1, 0, 1); STAGE_A(1, 1, 1);
  asm volatile("s_waitcnt vmcnt(4)" ::: "memory");  // tile0 landed
  __builtin_amdgcn_s_barrier();

  for (int t = 0; t < 32; ++t) {
    const int cur = t & 1;
    const bf16* as = &sm[0][0][0][0] + cur * 16384;
    const bf16* bs = &sm[1][0][0][0] + cur * 16384;
    bf16x8 a0[4][2], a1[4][2], b0[2][2], b1[2][2];

    // ---- ph0: q(0,0) ----
#pragma unroll
    for (int i = 0; i < 4; ++i) {
      a0[i][0] = *(const bf16x8*)(as + arow + i * 1024 + c0);
      a0[i][1] = *(const bf16x8*)(as + arow + i * 1024 + c1);
    }
#pragma unroll
    for (int j = 0; j < 2; ++j) {
      b0[j][0] = *(const bf16x8*)(bs + brow + j * 1024 + c0);
      b0[j][1] = *(const bf16x8*)(bs + brow + j * 1024 + c1);
    }
    if (t < 31) STAGE_B(1 - cur, 0, t + 1);
    asm volatile("s_waitcnt lgkmcnt(8)" ::: "memory");
    __builtin_amdgcn_s_barrier();
    asm volatile("s_waitcnt lgkmcnt(0)" ::: "memory");
    __builtin_amdgcn_s_setprio(1);
#pragma unroll
    for (int ks = 0; ks < 2; ++ks)
#pragma unroll
      for (int i = 0; i < 4; ++i)
#pragma unroll
        for (int j = 0; j < 2; ++j) acc[i][j] = MFMA16(a0[i][ks], b0[j][ks], acc[i][j]);
    __builtin_amdgcn_s_setprio(0);
    __builtin_amdgcn_s_barrier();

    // ---- ph1: q(0,1) ----
#pragma unroll
    for (int j = 0; j < 2; ++j) {
      b1[j][0] = *(const bf16x8*)(bs + brow + (2 + j) * 1024 + c0);
      b1[j][1] = *(const bf16x8*)(bs + brow + (2 + j) * 1024 + c1);
    }
    if (t < 31) STAGE_B(1 - cur, 1, t + 1);
    __builtin_amdgcn_s_barrier();
    asm volatile("s_waitcnt lgkmcnt(0)" ::: "memory");
    __builtin_amdgcn_s_setprio(1);
#pragma unroll
    for (int ks = 0; ks < 2; ++ks)
#pragma unroll
      for (int i = 0; i < 4; ++i)
#pragma unroll
        for (int j = 0; j < 2; ++j) acc[i][2 + j] = MFMA16(a0[i][ks], b1[j][ks], acc[i][2 + j]);
    __builtin_amdgcn_s_setprio(0);
    __builtin_amdgcn_s_barrier();

    // ---- ph2: q(1,0) ----
#pragma unroll
    for (int i = 0; i < 4; ++i) {
      a1[i][0] = *(const bf16x8*)(as + arow + (4 + i) * 1024 + c0);
      a1[i][1] = *(const bf16x8*)(as + arow + (4 + i) * 1024 + c1);
    }
    __builtin_amdgcn_s_barrier();
    asm volatile("s_waitcnt lgkmcnt(0)" ::: "memory");
    __builtin_amdgcn_s_setprio(1);
#pragma unroll
    for (int ks = 0; ks < 2; ++ks)
#pragma unroll
      for (int i = 0; i < 4; ++i)
#pragma unroll
        for (int j = 0; j < 2; ++j) acc[4 + i][j] = MFMA16(a1[i][ks], b0[j][ks], acc[4 + i][j]);
    __builtin_amdgcn_s_setprio(0);
    __builtin_amdgcn_s_barrier();

    // ---- ph3: q(1,1) + boundary ----
    __builtin_amdgcn_s_setprio(1);
#pragma unroll
    for (int ks = 0; ks < 2; ++ks)
#pragma unroll
      for (int i = 0; i < 4; ++i)
#pragma unroll
        for (int j = 0; j < 2; ++j) acc[4 + i][2 + j] = MFMA16(a1[i][ks], b1[j][ks], acc[4 + i][2 + j]);
    __builtin_amdgcn_s_setprio(0);
    if (t < 30) {
      STAGE_A(cur, 0, t + 2); STAGE_A(cur, 1, t + 2);
      asm volatile("s_waitcnt vmcnt(4)" ::: "memory");  // t+1 landed
      __builtin_amdgcn_s_barrier();
    } else if (t == 30) {
      asm volatile("s_waitcnt vmcnt(0)" ::: "memory");
      __builtin_amdgcn_s_barrier();
    }
  }

#pragma unroll
  for (int i = 0; i < 8; ++i)
#pragma unroll
    for (int r = 0; r < 4; ++r) {
      const size_t base = (size_t)(m0 + wr * 128 + i * 16 + quad * 4 + r) * 4096
                        + n0 + wc * 64 + l15;
#pragma unroll
      for (int j = 0; j < 4; ++j) qk[base + j * 16] = (bf16)acc[i][j][r];
    }
}

// ---------------- thin GEMM: 256x128, 2-K-tile deepened 4-phase -------------
// OUTMODE 0: V GEMM -> vt[b][f][n] via LDS transpose. OUTMODE 1: out-proj,
// fp32 direct store. Iteration u covers tiles e=2u (bufs 0) and o=2u+1
// (bufs 1). Per phase: {ds_reads; lgkmcnt(0); barrier; stage; setprio(1);
// 16 MFMA; setprio(0); [vmcnt]; barrier}. Staging spread 1 half-stage/phase:
// ph1 A(e+2), ph2 B(e+2), ph3 A(o+2), bnd B(o+2). Counted waits: vmcnt(4) at
// ph1-end (forces A(o),B(o), staged 3-4 phases prior), vmcnt(6) at boundary
// (forces A(e+2),B(e+2), staged 5-6 phases prior). Never vmcnt(0) until the
// final iteration. Ledger: 6 loads outstanding entering each iteration.
template <int OUTMODE>
__global__ __launch_bounds__(512, 2)
void gemm_thin(const bf16* __restrict__ A, const bf16* __restrict__ B,
               bf16* __restrict__ vt, float* __restrict__ C) {
  __shared__ __attribute__((aligned(16))) bf16 smA[2][256][64];  // 64 KiB
  __shared__ __attribute__((aligned(16))) bf16 smB[2][128][64];  // 32 KiB
  const int tid = threadIdx.x;
  const int lane = tid & 63;
  const int wid = tid >> 6;
  const int quad = lane >> 4, l15 = lane & 15;
  const int wr = wid >> 1, wc = wid & 1;   // 4M x 2N waves; wave tile 64x64

  const int lb = (blockIdx.x & 7) * 32 + (blockIdx.x >> 3);
  const int bm = lb >> 4, bn = lb & 15;
  const int m0 = bm * 256, n0 = bn * 128;

  const int srow = tid >> 3;
  const int kswz8 = ((tid & 7) ^ (srow & 7)) * 8;
  const bf16* Ag = A + (size_t)(m0 + srow) * 2048 + kswz8;
  const bf16* Bg = B + (size_t)(n0 + srow) * 2048 + kswz8;
  bf16* ldsA = &smA[0][0][0] + tid * 8;
  bf16* ldsB = &smB[0][0][0] + tid * 8;

  f32x4 acc[4][4];
#pragma unroll
  for (int i = 0; i < 4; ++i)
#pragma unroll
    for (int j = 0; j < 4; ++j) acc[i][j] = {0.f, 0.f, 0.f, 0.f};

  const int r7 = l15 & 7;
  const int c0 = (quad ^ r7) * 8;        // ks=0 swizzled chunk
  const int c1 = ((4 + quad) ^ r7) * 8;  // ks=1
  const int arow = (wr * 64 + l15) * 64;
  const int brow = (wc * 64 + l15) * 64;

  // prologue: tiles 0 (bufs 0) and 1 (bufs 1); issue order matters for vmcnt.
  STAGE_A(0, 0, 0); STAGE_A(0, 1, 0); STAGE_BS(0, 0);
  STAGE_A(1, 0, 1); STAGE_A(1, 1, 1); STAGE_BS(1, 1);
  asm volatile("s_waitcnt vmcnt(6)" ::: "memory");  // tile0 landed; tile1 in flight
  __builtin_amdgcn_s_barrier();

  const bf16* ae = &smA[0][0][0];
  const bf16* ao = &smA[1][0][0];
  const bf16* be = &smB[0][0][0];
  const bf16* bo = &smB[1][0][0];

  for (int u = 0; u < 16; ++u) {
    const int e = 2 * u;
    const bool st = (u < 15);
    bf16x8 afe[4][2], bfe[4][2], afo[4][2], bfo[4][2];

    // ---- ph0: read A(e) all + B(e) ks0; MFMA (e, ks0) ----
#pragma unroll
    for (int i = 0; i < 4; ++i) {
      afe[i][0] = *(const bf16x8*)(ae + arow + i * 1024 + c0);
      afe[i][1] = *(const bf16x8*)(ae + arow + i * 1024 + c1);
    }
#pragma unroll
    for (int j = 0; j < 4; ++j)
      bfe[j][0] = *(const bf16x8*)(be + brow + j * 1024 + c0);
    asm volatile("s_waitcnt lgkmcnt(0)" ::: "memory");
    __builtin_amdgcn_s_barrier();
    __builtin_amdgcn_s_setprio(1);
#pragma unroll
    for (int i = 0; i < 4; ++i)
#pragma unroll
      for (int j = 0; j < 4; ++j) acc[i][j] = MFMA16(afe[i][0], bfe[j][0], acc[i][j]);
    __builtin_amdgcn_s_setprio(0);
    __builtin_amdgcn_s_barrier();

    // ---- ph1: read B(e) ks1; stage A(e+2) -> bufA0; MFMA (e, ks1); vmcnt ----
#pragma unroll
    for (int j = 0; j < 4; ++j)
      bfe[j][1] = *(const bf16x8*)(be + brow + j * 1024 + c1);
    asm volatile("s_waitcnt lgkmcnt(0)" ::: "memory");
    __builtin_amdgcn_s_barrier();
    if (st) { STAGE_A(0, 0, e + 2); STAGE_A(0, 1, e + 2); }
    __builtin_amdgcn_s_setprio(1);
#pragma unroll
    for (int i = 0; i < 4; ++i)
#pragma unroll
      for (int j = 0; j < 4; ++j) acc[i][j] = MFMA16(afe[i][1], bfe[j][1], acc[i][j]);
    __builtin_amdgcn_s_setprio(0);
    if (st) { asm volatile("s_waitcnt vmcnt(4)" ::: "memory"); }   // A(o),B(o) landed
    else    { asm volatile("s_waitcnt vmcnt(0)" ::: "memory"); }
    __builtin_amdgcn_s_barrier();

    // ---- ph2: read A(o) all + B(o) ks0; stage B(e+2) -> bufB0; MFMA (o,ks0) ----
#pragma unroll
    for (int i = 0; i < 4; ++i) {
      afo[i][0] = *(const bf16x8*)(ao + arow + i * 1024 + c0);
      afo[i][1] = *(const bf16x8*)(ao + arow + i * 1024 + c1);
    }
#pragma unroll
    for (int j = 0; j < 4; ++j)
      bfo[j][0] = *(const bf16x8*)(bo + brow + j * 1024 + c0);
    asm volatile("s_waitcnt lgkmcnt(0)" ::: "memory");
    __builtin_amdgcn_s_barrier();
    if (st) STAGE_BS(0, e + 2);
    __builtin_amdgcn_s_setprio(1);
#pragma unroll
    for (int i = 0; i < 4; ++i)
#pragma unroll
      for (int j = 0; j < 4; ++j) acc[i][j] = MFMA16(afo[i][0], bfo[j][0], acc[i][j]);
    __builtin_amdgcn_s_setprio(0);
    __builtin_amdgcn_s_barrier();

    // ---- ph3: read B(o) ks1; stage A(o+2) -> bufA1; MFMA (o, ks1) ----
#pragma unroll
    for (int j = 0; j < 4; ++j)
      bfo[j][1] = *(const bf16x8*)(bo + brow + j * 1024 + c1);
    asm volatile("s_waitcnt lgkmcnt(0)" ::: "memory");
    __builtin_amdgcn_s_barrier();
    if (st) { STAGE_A(1, 0, e + 3); STAGE_A(1, 1, e + 3); }
    __builtin_amdgcn_s_setprio(1);
#pragma unroll
    for (int i = 0; i < 4; ++i)
#pragma unroll
      for (int j = 0; j < 4; ++j) acc[i][j] = MFMA16(afo[i][1], bfo[j][1], acc[i][j]);
    __builtin_amdgcn_s_setprio(0);

    // ---- boundary: stage B(o+2) -> bufB1; counted wait ----
    if (st) {
      STAGE_BS(1, e + 3);
      asm volatile("s_waitcnt vmcnt(6)" ::: "memory");  // A(e+2),B(e+2) landed
      __builtin_amdgcn_s_barrier();
    }
  }

  if constexpr (OUTMODE == 0) {
    // ---- V epilogue: transpose 256x128 through LDS -> vt[b][f][n] ----
    __syncthreads();
    bf16* T = &smA[0][0][0];  // [128 f][256 n swizzled] = 64 KiB
#pragma unroll
    for (int i = 0; i < 4; ++i)
#pragma unroll
      for (int r = 0; r < 4; ++r) {
        const int nl = wr * 64 + i * 16 + quad * 4 + r;
#pragma unroll
        for (int j = 0; j < 4; ++j) {
          const int fl = wc * 64 + j * 16 + l15;
          T[fl * 256 + ((((nl >> 3) ^ (fl & 31)) << 3) | (nl & 7))] = (bf16)acc[i][j][r];
        }
      }
    __syncthreads();
    const int f0g = n0, nb0 = m0 & 2047, b = m0 >> 11;
#pragma unroll
    for (int c = 0; c < 8; ++c) {
      const int idx = c * 512 + tid;
      const int fl = idx >> 5, nb = idx & 31;
      bf16x8 o = *(const bf16x8*)(T + fl * 256 + ((nb ^ (fl & 31)) << 3));
      *(bf16x8*)(vt + (size_t)(b * 2048 + f0g + fl) * 2048 + nb0 + nb * 8) = o;
    }
  } else {
    // ---- out-proj epilogue: fp32 direct store ----
#pragma unroll
    for (int i = 0; i < 4; ++i) {
#pragma unroll
      for (int r = 0; r < 4; ++r) {
        const size_t base = (size_t)(m0 + wr * 64 + i * 16 + quad * 4 + r) * 2048
                          + n0 + wc * 64 + l15;
#pragma unroll
        for (int j = 0; j < 4; ++j) C[base + j * 16] = (float)acc[i][j][r];
      }
    }
  }
}

// ---------------- flash attention, causal, S^T, double-buffered --------------
// (unchanged from R4 — defer-max T13)
__global__ __launch_bounds__(256, 2)
void attn_kernel(const bf16* __restrict__ qk, const bf16* __restrict__ vt,
                 bf16* __restrict__ yb) {
  constexpr int NSEQ = 2048, E = 2048, QKS = 4096;
  __shared__ __attribute__((aligned(16))) bf16 Ks[2][64 * 128];   // [tok][d], XOR-swizzled
  __shared__ __attribute__((aligned(16))) bf16 Vs[2][128 * 64];   // [d][tok], XOR-swizzled
  const int tid = threadIdx.x;
  const int wave = tid >> 6, lane = tid & 63;
  const int l31 = lane & 31, half = lane >> 5;
  const int id = blockIdx.x;
  const int slot = (id >> 5) & 15;
  const int bh = (id & 7) | (((id >> 3) & 3) << 3);
  const int b = bh >> 4, h = bh & 15;
  const int qt = (slot < 8) ? slot : 23 - slot;
  const float c1 = 0.08838834764831845f * 1.44269504088896f;  // scale * log2(e)

  const int krow_s = tid >> 4, kch_s = tid & 15;  // K: 16 chunks/row
  const int vrow_s = tid >> 3, vch_s = tid & 7;   // V: 8 chunks/row
  const bf16* kg = qk + (size_t)(b * NSEQ) * QKS + 2048 + h * 128;
  const bf16* vg = vt + (size_t)b * E * NSEQ + (size_t)(h * 128) * NSEQ;

  const int diag = 2 * qt + (wave >> 1);
  const int ktmax = 2 * qt + 1;

  {
    bf16* kdst = Ks[0] + tid * 8;
    bf16* vdst = Vs[0] + tid * 8;
#pragma unroll
    for (int p = 0; p < 4; ++p) {
      int r = p * 16 + krow_s;
      async_load16(kg + (size_t)r * QKS + (kch_s ^ (r & 7)) * 8, kdst + p * 2048);
    }
#pragma unroll
    for (int p = 0; p < 4; ++p) {
      int r = p * 32 + vrow_s;
      async_load16(vg + (size_t)r * NSEQ + (vch_s ^ (r & 7)) * 8, vdst + p * 2048);
    }
  }

  const int qrow = qt * 128 + wave * 32 + l31;
  bf16x8 qf[8];
  {
    const bf16* qp = qk + (size_t)(b * NSEQ + qrow) * QKS + h * 128 + half * 8;
#pragma unroll
    for (int k8 = 0; k8 < 8; ++k8) qf[k8] = *(const bf16x8*)(qp + k8 * 16);
  }

  float m = -3.0e38f, l = 0.f;
  f32x16 accO[4];
#pragma unroll
  for (int md = 0; md < 4; ++md)
#pragma unroll
    for (int r = 0; r < 16; ++r) accO[md][r] = 0.f;

  union PU { unsigned u; bf16x2 h; };
  union FU { bf16x8 v; unsigned u[4]; };

  for (int kt = 0; kt <= ktmax; ++kt) {
    const int cur = kt & 1;
    __syncthreads();

    if (kt < ktmax) {
      const int nxt = kt + 1;
      bf16* kdst = Ks[1 - cur] + tid * 8;
      bf16* vdst = Vs[1 - cur] + tid * 8;
#pragma unroll
      for (int p = 0; p < 4; ++p) {
        int r = p * 16 + krow_s;
        async_load16(kg + (size_t)(nxt * 64 + r) * QKS + (kch_s ^ (r & 7)) * 8, kdst + p * 2048);
      }
#pragma unroll
      for (int p = 0; p < 4; ++p) {
        int r = p * 32 + vrow_s;
        async_load16(vg + (size_t)r * NSEQ + nxt * 64 + (vch_s ^ (r & 7)) * 8, vdst + p * 2048);
      }
    }

    if (kt > diag) continue;

    const bf16* ks = Ks[cur];
    const bf16* vs = Vs[cur];

    f32x16 st[2];
#pragma unroll
    for (int mt = 0; mt < 2; ++mt)
#pragma unroll
      for (int r = 0; r < 16; ++r) st[mt][r] = 0.f;
#pragma unroll
    for (int k8 = 0; k8 < 8; ++k8) {
#pragma unroll
      for (int mt = 0; mt < 2; ++mt) {
        int row = mt * 32 + l31;
        int sl = (k8 * 2 + half) ^ (row & 7);
        bf16x8 kf = *(const bf16x8*)(ks + row * 128 + sl * 8);
        st[mt] = MFMA32(kf, qf[k8], st[mt]);
      }
    }

    if (kt == diag) {
#pragma unroll
      for (int mt = 0; mt < 2; ++mt)
#pragma unroll
        for (int r = 0; r < 16; ++r) {
          int t = kt * 64 + mt * 32 + (r & 3) + 8 * (r >> 2) + 4 * half;
          if (t > qrow) st[mt][r] = -3.0e38f;
        }
    }

    // ---- online softmax with defer-max (T13) ----
    float mx = -3.0e38f;
#pragma unroll
    for (int mt = 0; mt < 2; ++mt)
#pragma unroll
      for (int r = 0; r < 16; ++r) mx = fmaxf(mx, st[mt][r]);
    mx = fmaxf(mx, __shfl_xor(mx, 32));

    const bool noresc = __all((mx - m) * c1 <= 8.0f);
    const float mnew = noresc ? m : fmaxf(m, mx);
    const float mc = mnew * c1;

    float psum = 0.f;
    unsigned pown[2][4][2];
#pragma unroll
    for (int mt = 0; mt < 2; ++mt)
#pragma unroll
      for (int qd = 0; qd < 4; ++qd)
#pragma unroll
        for (int pr = 0; pr < 2; ++pr) {
          float p0 = exp2f(st[mt][qd * 4 + pr * 2] * c1 - mc);
          float p1 = exp2f(st[mt][qd * 4 + pr * 2 + 1] * c1 - mc);
          psum += p0 + p1;
          PU a; a.h[0] = (bf16)p0; a.h[1] = (bf16)p1;
          pown[mt][qd][pr] = a.u;
        }
    psum += __shfl_xor(psum, 32);

    if (!noresc) {
      const float alpha = exp2f((m - mnew) * c1);
      l *= alpha;
      m = mnew;
#pragma unroll
      for (int md = 0; md < 4; ++md)
#pragma unroll
        for (int r = 0; r < 16; ++r) accO[md][r] *= alpha;
    }
    l += psum;

#pragma unroll
    for (int mt = 0; mt < 2; ++mt)
#pragma unroll
      for (int c = 0; c < 2; ++c) {
        const int qa = 2 * c, qb = 2 * c + 1;
        unsigned ra0 = __shfl_xor(pown[mt][qa][0], 32);
        unsigned ra1 = __shfl_xor(pown[mt][qa][1], 32);
        unsigned rb0 = __shfl_xor(pown[mt][qb][0], 32);
        unsigned rb1 = __shfl_xor(pown[mt][qb][1], 32);
        FU f;
        f.u[0] = half ? rb0 : pown[mt][qa][0];
        f.u[1] = half ? rb1 : pown[mt][qa][1];
        f.u[2] = half ? pown[mt][qb][0] : ra0;
        f.u[3] = half ? pown[mt][qb][1] : ra1;
        const int kk = mt * 2 + c;
#pragma unroll
        for (int md = 0; md < 4; ++md) {
          int row = md * 32 + l31;
          bf16x8 vf = *(const bf16x8*)(vs + row * 64 + (((kk * 2 + half) ^ (row & 7)) * 8));
          accO[md] = MFMA32(vf, f.v, accO[md]);
        }
      }
  }

  float invl = 1.0f / l;
  bf16* yp = yb + (size_t)(b * NSEQ + qrow) * E + h * 128;
#pragma unroll
  for (int md = 0; md < 4; ++md)
#pragma unroll
    for (int rq = 0; rq < 4; ++rq) {
      bf16x4 o;
#pragma unroll
      for (int i = 0; i < 4; ++i) o[i] = (bf16)(accO[md][rq * 4 + i] * invl);
      *(bf16x4*)(yp + md * 32 + rq * 8 + half * 4) = o;
    }
}

// ---------------- launch ----------------
extern "C" void kernel_launch(void* const* d_in, const int* in_sizes, int n_in,
                              void* d_out, int out_size, void* d_ws, size_t ws_size,
                              hipStream_t stream) {
  const float* x    = (const float*)d_in[0];
  const float* Wq   = (const float*)d_in[1];
  const float* Wkv  = (const float*)d_in[2];
  const float* Wout = (const float*)d_in[3];
  float* out = (float*)d_out;

  constexpr size_t NX = (size_t)2 * 2048 * 2048;  // 8388608
  constexpr size_t NW = (size_t)2048 * 2048;      // 4194304

  bf16* xb     = (bf16*)d_ws;
  bf16* wqkvb  = xb + NX;          // [6144 x 2048] = Wq rows then Wkv rows
  bf16* woutb  = wqkvb + 3 * NW;
  bf16* qk_b   = woutb + NW;       // [4096 x 4096]: q | k per row
  bf16* y_b    = qk_b + 2 * NX;
  bf16* vt_b   = y_b + NX;         // [b, f, n] = [2][2048][2048]

  cast_all_kernel<<<12288, 256, 0, stream>>>(x, Wq, Wkv, Wout, xb, wqkvb, woutb);

  // q|k = x @ [Wq; Wk]^T -> qk_b (stride 4096); one exact 256-block round
  gemm_qk_8phase<<<256, 512, 0, stream>>>(xb, wqkvb, qk_b);
  // V = x @ Wv^T -> vt_b transposed; deepened thin GEMM, one exact round
  gemm_thin<0><<<256, 512, 0, stream>>>(xb, wqkvb + (size_t)4096 * 2048, vt_b, nullptr);
  // attention -> y [4096, 2048] bf16
  attn_kernel<<<512, 256, 0, stream>>>(qk_b, vt_b, y_b);
  // out = y @ Wout^T : fp32; deepened thin GEMM, one exact round
  gemm_thin<1><<<256, 512, 0, stream>>>(y_b, woutb, nullptr, out);
}